// Round 12
// baseline (335.669 us; speedup 1.0000x reference)
//
#include <hip/hip_runtime.h>

#define LSEQ 200
#define KCAP 4
#define NVOC 100000

// ---------------------------------------------------------------------------
// Kernel 1: P = (E with row 0 zeroed) @ S, P: (NVOC, 64) in workspace.
// Verbatim round-6 version (passed; ~13 us). 64x64 tile, 4x4 per-thread.
// ---------------------------------------------------------------------------
__global__ __launch_bounds__(256) void precompute_P(
    const float* __restrict__ E, const float* __restrict__ S,
    float* __restrict__ P)
{
    __shared__ __align__(16) float Sl[64 * 64];   // Sl[e*64 + d]
    __shared__ __align__(16) float Et[64 * 68];   // Et[e*68 + r] = E[(vbase+r)*64+e]
    const int tid   = threadIdx.x;
    const int vbase = blockIdx.x * 64;

    #pragma unroll
    for (int t = tid; t < 4096; t += 256) Sl[t] = S[t];
    #pragma unroll
    for (int t = tid; t < 4096; t += 256) {
        int r = t >> 6, e = t & 63;               // wave: r fixed, e=lane -> coalesced
        int v = vbase + r;
        Et[e * 68 + r] = (v < NVOC) ? E[v * 64 + e] : 0.f;
    }
    __syncthreads();

    const int rq = tid >> 4;                      // 16 row-quads
    const int cq = tid & 15;                      // 16 col-quads
    float a00=0,a01=0,a02=0,a03=0, a10=0,a11=0,a12=0,a13=0;
    float a20=0,a21=0,a22=0,a23=0, a30=0,a31=0,a32=0,a33=0;
    #pragma unroll 8
    for (int e = 0; e < 64; e++) {
        float4 ev = *(const float4*)(Et + e * 68 + rq * 4);
        float4 sv = *(const float4*)(Sl + e * 64 + cq * 4);
        a00 = fmaf(ev.x, sv.x, a00); a01 = fmaf(ev.x, sv.y, a01);
        a02 = fmaf(ev.x, sv.z, a02); a03 = fmaf(ev.x, sv.w, a03);
        a10 = fmaf(ev.y, sv.x, a10); a11 = fmaf(ev.y, sv.y, a11);
        a12 = fmaf(ev.y, sv.z, a12); a13 = fmaf(ev.y, sv.w, a13);
        a20 = fmaf(ev.z, sv.x, a20); a21 = fmaf(ev.z, sv.y, a21);
        a22 = fmaf(ev.z, sv.z, a22); a23 = fmaf(ev.z, sv.w, a23);
        a30 = fmaf(ev.w, sv.x, a30); a31 = fmaf(ev.w, sv.y, a31);
        a32 = fmaf(ev.w, sv.z, a32); a33 = fmaf(ev.w, sv.w, a33);
    }

    const int r0 = vbase + rq * 4;
    float4 o0 = make_float4(a00, a01, a02, a03);
    float4 o1 = make_float4(a10, a11, a12, a13);
    float4 o2 = make_float4(a20, a21, a22, a23);
    float4 o3 = make_float4(a30, a31, a32, a33);
    if (r0 == 0) o0 = make_float4(0.f, 0.f, 0.f, 0.f);  // padding_idx=0
    if (r0 + 0 < NVOC) *(float4*)(P + (r0 + 0) * 64 + cq * 4) = o0;
    if (r0 + 1 < NVOC) *(float4*)(P + (r0 + 1) * 64 + cq * 4) = o1;
    if (r0 + 2 < NVOC) *(float4*)(P + (r0 + 2) * 64 + cq * 4) = o2;
    if (r0 + 3 < NVOC) *(float4*)(P + (r0 + 3) * 64 + cq * 4) = o3;
}

// ---------------------------------------------------------------------------
// Kernel 2: TWO batch rows per block (256 threads = 4 waves), grid 2048.
// r11 post-mortem: hp-in-registers is right; occupancy is pinned to the
// declared min waves/EU and min>=5 force-spills hp. So: more ILP per wave at
// fixed occupancy. Each wave carries rows b0,b1 as two independent chains
// through every phase; barriers per row halve; MLP/D weight streams are
// loaded once for two rows. Per-row arithmetic VERBATIM r6 (absmax 4.88e-4).
// Canaries: VGPR <= 64 + WRITE >> 4 MB = spill (fallback: (256,3)).
//
// LDS: POOL[2][4336] = 34688 B. Per-row layout (r6's):
//   +0 Bm[4*208] | +832 W4[200*4] | +1632 caps4[64*4] | +1888 bigneg[200]
//   | +2088 idxs(int[200]) | +2288 SC{part[1024] | h4=+1024}
// ---------------------------------------------------------------------------
#define ROWOFF 4336

__global__ __launch_bounds__(256, 4) void mind_row2(
    const int*   __restrict__ his, const float* __restrict__ P,
    const float* __restrict__ B0,  const float* __restrict__ W1,
    const float* __restrict__ b1,  const float* __restrict__ W2,
    const float* __restrict__ b2,  float* __restrict__ out)
{
    __shared__ __align__(16) float POOL[2 * ROWOFF];

    const int b0   = blockIdx.x * 2;
    const int tid  = threadIdx.x;
    const int lane = tid & 63;
    const int wv   = tid >> 6;

    // ---- setup (both rows) -------------------------------------------------
    #pragma unroll
    for (int rr = 0; rr < 2; rr++) {
        float* Bm     = POOL + rr * ROWOFF;
        float* bigneg = POOL + rr * ROWOFF + 1888;
        int*   idxs   = (int*)(POOL + rr * ROWOFF + 2088);
        if (tid < LSEQ) {
            int id = his[(b0 + rr) * LSEQ + tid];
            idxs[tid]   = id;
            bigneg[tid] = (id != 0) ? 0.f : -1e30f;
            #pragma unroll
            for (int k = 0; k < KCAP; k++) Bm[k * 208 + tid] = B0[k * LSEQ + tid];
        }
    }
    __syncthreads();

    // ---- gather: wave covers l in [wv*50,wv*50+50), lane = d; both rows ----
    float hp0[50], hp1[50];
    {
        const int* idxs0 = (const int*)(POOL + 2088);
        const int* idxs1 = (const int*)(POOL + ROWOFF + 2088);
        #pragma unroll
        for (int i = 0; i < 50; i++) {
            int l = wv * 50 + i;
            hp0[i] = P[idxs0[l] * 64 + lane];   // 256B coalesced per wave
            hp1[i] = P[idxs1[l] * 64 + lane];
        }
    }

    for (int r = 0; r < 3; r++) {
        // A: masked softmax, capsule k = wv; both rows (independent chains)
        #pragma unroll
        for (int rr = 0; rr < 2; rr++) {
            const float* Bk     = POOL + rr * ROWOFF + wv * 208;
            const float* bigneg = POOL + rr * ROWOFF + 1888;
            float*       W4     = POOL + rr * ROWOFF + 832;
            float x0 = Bk[lane]       + bigneg[lane];
            float x1 = Bk[lane + 64]  + bigneg[lane + 64];
            float x2 = Bk[lane + 128] + bigneg[lane + 128];
            float x3 = (lane < 8) ? (Bk[lane + 192] + bigneg[lane + 192]) : -3.0e38f;
            float m = fmaxf(fmaxf(x0, x1), fmaxf(x2, x3));
            #pragma unroll
            for (int off = 32; off; off >>= 1) m = fmaxf(m, __shfl_xor(m, off, 64));
            float e0 = __expf(x0 - m), e1 = __expf(x1 - m), e2 = __expf(x2 - m);
            float e3 = (lane < 8) ? __expf(x3 - m) : 0.f;
            float ssum = e0 + e1 + e2 + e3;
            #pragma unroll
            for (int off = 32; off; off >>= 1) ssum += __shfl_xor(ssum, off, 64);
            float inv = 1.f / ssum;
            W4[lane * 4 + wv]         = e0 * inv;
            W4[(lane + 64) * 4 + wv]  = e1 * inv;
            W4[(lane + 128) * 4 + wv] = e2 * inv;
            if (lane < 8) W4[(lane + 192) * 4 + wv] = e3 * inv;
        }
        __syncthreads();

        // B: caps partials from register-resident hisP; twin accumulators
        {
            const float* W4a = POOL + 832;
            const float* W4b = POOL + ROWOFF + 832;
            float a0 = 0, a1 = 0, a2 = 0, a3 = 0;
            float c0 = 0, c1 = 0, c2 = 0, c3 = 0;
            #pragma unroll
            for (int i = 0; i < 50; i++) {
                int l = wv * 50 + i;
                float4 wa = *(const float4*)(W4a + l * 4);   // broadcast b128
                float4 wb = *(const float4*)(W4b + l * 4);
                float  va = hp0[i];
                float  vb = hp1[i];
                a0 = fmaf(wa.x, va, a0);
                a1 = fmaf(wa.y, va, a1);
                a2 = fmaf(wa.z, va, a2);
                a3 = fmaf(wa.w, va, a3);
                c0 = fmaf(wb.x, vb, c0);
                c1 = fmaf(wb.y, vb, c1);
                c2 = fmaf(wb.z, vb, c2);
                c3 = fmaf(wb.w, vb, c3);
            }
            float* parta = POOL + 2288;
            float* partb = POOL + ROWOFF + 2288;
            parta[wv * 256 + lane]       = a0;
            parta[wv * 256 + 64 + lane]  = a1;
            parta[wv * 256 + 128 + lane] = a2;
            parta[wv * 256 + 192 + lane] = a3;
            partb[wv * 256 + lane]       = c0;
            partb[wv * 256 + 64 + lane]  = c1;
            partb[wv * 256 + 128 + lane] = c2;
            partb[wv * 256 + 192 + lane] = c3;
        }
        __syncthreads();

        // C: reduce partials + squash; thread = (k = wv, d = lane); both rows
        #pragma unroll
        for (int rr = 0; rr < 2; rr++) {
            const float* part  = POOL + rr * ROWOFF + 2288;
            float*       caps4 = POOL + rr * ROWOFF + 1632;
            float c = part[wv * 64 + lane]       + part[256 + wv * 64 + lane]
                    + part[512 + wv * 64 + lane] + part[768 + wv * 64 + lane];
            float n2 = c * c;
            #pragma unroll
            for (int off = 32; off; off >>= 1) n2 += __shfl_xor(n2, off, 64);
            float n  = sqrtf(n2);
            float sc = n2 / ((1.f + n2) * n + 1e-9f);
            c *= sc;
            caps4[lane * 4 + wv] = c;
        }
        __syncthreads();

        if (r < 2) {
            // D: B[k][l] += caps[k].hisP[l] (thread per l; per-row verbatim r6)
            if (tid < LSEQ) {
                #pragma unroll
                for (int rr = 0; rr < 2; rr++) {
                    const int*   idxs  = (const int*)(POOL + rr * ROWOFF + 2088);
                    const float* caps4 = POOL + rr * ROWOFF + 1632;
                    float*       Bm    = POOL + rr * ROWOFF;
                    const float4* __restrict__ rowp =
                        (const float4*)(P + idxs[tid] * 64);
                    float d0 = 0, d1 = 0, d2 = 0, d3 = 0;
                    #pragma unroll
                    for (int j = 0; j < 16; j++) {
                        float4 v = rowp[j];
                        {
                            float4 c = *(const float4*)(caps4 + (j * 4 + 0) * 4);
                            d0 = fmaf(c.x, v.x, d0); d1 = fmaf(c.y, v.x, d1);
                            d2 = fmaf(c.z, v.x, d2); d3 = fmaf(c.w, v.x, d3);
                        }
                        {
                            float4 c = *(const float4*)(caps4 + (j * 4 + 1) * 4);
                            d0 = fmaf(c.x, v.y, d0); d1 = fmaf(c.y, v.y, d1);
                            d2 = fmaf(c.z, v.y, d2); d3 = fmaf(c.w, v.y, d3);
                        }
                        {
                            float4 c = *(const float4*)(caps4 + (j * 4 + 2) * 4);
                            d0 = fmaf(c.x, v.z, d0); d1 = fmaf(c.y, v.z, d1);
                            d2 = fmaf(c.z, v.z, d2); d3 = fmaf(c.w, v.z, d3);
                        }
                        {
                            float4 c = *(const float4*)(caps4 + (j * 4 + 3) * 4);
                            d0 = fmaf(c.x, v.w, d0); d1 = fmaf(c.y, v.w, d1);
                            d2 = fmaf(c.z, v.w, d2); d3 = fmaf(c.w, v.w, d3);
                        }
                    }
                    Bm[tid]       += d0;
                    Bm[208 + tid] += d1;
                    Bm[416 + tid] += d2;
                    Bm[624 + tid] += d3;
                }
            }
            __syncthreads();
        }
    }

    // MLP layer 1: shared W1 load feeds both rows' caps
    {
        const int f = tid;
        const float* caps4a = POOL + 1632;
        const float* caps4b = POOL + ROWOFF + 1632;
        float* h4a = POOL + 2288 + 1024;
        float* h4b = POOL + ROWOFF + 2288 + 1024;
        float h0a = 0, h1a = 0, h2a = 0, h3a = 0;
        float h0b = 0, h1b = 0, h2b = 0, h3b = 0;
        #pragma unroll 8
        for (int d = 0; d < 64; d++) {
            float  w  = W1[d * 256 + f];                     // one load, 2 rows
            float4 ca = *(const float4*)(caps4a + d * 4);
            float4 cb = *(const float4*)(caps4b + d * 4);
            h0a = fmaf(ca.x, w, h0a); h1a = fmaf(ca.y, w, h1a);
            h2a = fmaf(ca.z, w, h2a); h3a = fmaf(ca.w, w, h3a);
            h0b = fmaf(cb.x, w, h0b); h1b = fmaf(cb.y, w, h1b);
            h2b = fmaf(cb.z, w, h2b); h3b = fmaf(cb.w, w, h3b);
        }
        float bb = b1[f];
        h0a = fmaxf(h0a + bb, 0.f); h1a = fmaxf(h1a + bb, 0.f);
        h2a = fmaxf(h2a + bb, 0.f); h3a = fmaxf(h3a + bb, 0.f);
        h0b = fmaxf(h0b + bb, 0.f); h1b = fmaxf(h1b + bb, 0.f);
        h2b = fmaxf(h2b + bb, 0.f); h3b = fmaxf(h3b + bb, 0.f);
        h4a[f * 4 + 0] = h0a; h4a[f * 4 + 1] = h1a;
        h4a[f * 4 + 2] = h2a; h4a[f * 4 + 3] = h3a;
        h4b[f * 4 + 0] = h0b; h4b[f * 4 + 1] = h1b;
        h4b[f * 4 + 2] = h2b; h4b[f * 4 + 3] = h3b;
    }
    __syncthreads();

    // MLP layer 2 partials: shared W2 load; q = wv covers f in [q*64,q*64+64)
    {
        const float* h4a = POOL + 2288 + 1024;
        const float* h4b = POOL + ROWOFF + 2288 + 1024;
        float o0a = 0, o1a = 0, o2a = 0, o3a = 0;
        float o0b = 0, o1b = 0, o2b = 0, o3b = 0;
        #pragma unroll 8
        for (int i = 0; i < 64; i++) {
            int f = wv * 64 + i;
            float  w   = W2[f * 64 + lane];                  // one load, 2 rows
            float4 hva = *(const float4*)(h4a + f * 4);      // broadcast b128
            float4 hvb = *(const float4*)(h4b + f * 4);
            o0a = fmaf(hva.x, w, o0a); o1a = fmaf(hva.y, w, o1a);
            o2a = fmaf(hva.z, w, o2a); o3a = fmaf(hva.w, w, o3a);
            o0b = fmaf(hvb.x, w, o0b); o1b = fmaf(hvb.y, w, o1b);
            o2b = fmaf(hvb.z, w, o2b); o3b = fmaf(hvb.w, w, o3b);
        }
        float* parta = POOL + 2288;
        float* partb = POOL + ROWOFF + 2288;
        parta[wv * 256 + lane]       = o0a;
        parta[wv * 256 + 64 + lane]  = o1a;
        parta[wv * 256 + 128 + lane] = o2a;
        parta[wv * 256 + 192 + lane] = o3a;
        partb[wv * 256 + lane]       = o0b;
        partb[wv * 256 + 64 + lane]  = o1b;
        partb[wv * 256 + 128 + lane] = o2b;
        partb[wv * 256 + 192 + lane] = o3b;
    }
    __syncthreads();
    #pragma unroll
    for (int rr = 0; rr < 2; rr++) {
        const float* part = POOL + rr * ROWOFF + 2288;
        float o = part[wv * 64 + lane]       + part[256 + wv * 64 + lane]
                + part[512 + wv * 64 + lane] + part[768 + wv * 64 + lane];
        out[(b0 + rr) * 256 + tid] = o + b2[lane];   // (b, k=wv, d=lane)
    }
}

extern "C" void kernel_launch(void* const* d_in, const int* in_sizes, int n_in,
                              void* d_out, int out_size, void* d_ws, size_t ws_size,
                              hipStream_t stream) {
    const int*   his = (const int*)  d_in[0];
    const float* E   = (const float*)d_in[1];
    const float* S   = (const float*)d_in[2];
    const float* B0  = (const float*)d_in[3];
    const float* W1  = (const float*)d_in[4];
    const float* b1  = (const float*)d_in[5];
    const float* W2  = (const float*)d_in[6];
    const float* b2  = (const float*)d_in[7];
    float* out = (float*)d_out;
    float* P   = (float*)d_ws;            // NVOC*64 floats = 25.6 MB scratch

    precompute_P<<<(NVOC + 63) / 64, 256, 0, stream>>>(E, S, P);
    mind_row2<<<2048, 256, 0, stream>>>(his, P, B0, W1, b1, W2, b2, out);
}

// Round 14
// 276.826 us; speedup vs baseline: 1.2126x; 1.2126x over previous
//
#include <hip/hip_runtime.h>

#define LSEQ 200
#define KCAP 4
#define NVOC 100000

// ---------------------------------------------------------------------------
// Kernel 1: P = (E with row 0 zeroed) @ S, P: (NVOC, 64) in workspace.
// Verbatim round-6 version (passed; ~13 us). 64x64 tile, 4x4 per-thread.
// ---------------------------------------------------------------------------
__global__ __launch_bounds__(256) void precompute_P(
    const float* __restrict__ E, const float* __restrict__ S,
    float* __restrict__ P)
{
    __shared__ __align__(16) float Sl[64 * 64];   // Sl[e*64 + d]
    __shared__ __align__(16) float Et[64 * 68];   // Et[e*68 + r] = E[(vbase+r)*64+e]
    const int tid   = threadIdx.x;
    const int vbase = blockIdx.x * 64;

    #pragma unroll
    for (int t = tid; t < 4096; t += 256) Sl[t] = S[t];
    #pragma unroll
    for (int t = tid; t < 4096; t += 256) {
        int r = t >> 6, e = t & 63;               // wave: r fixed, e=lane -> coalesced
        int v = vbase + r;
        Et[e * 68 + r] = (v < NVOC) ? E[v * 64 + e] : 0.f;
    }
    __syncthreads();

    const int rq = tid >> 4;                      // 16 row-quads
    const int cq = tid & 15;                      // 16 col-quads
    float a00=0,a01=0,a02=0,a03=0, a10=0,a11=0,a12=0,a13=0;
    float a20=0,a21=0,a22=0,a23=0, a30=0,a31=0,a32=0,a33=0;
    #pragma unroll 8
    for (int e = 0; e < 64; e++) {
        float4 ev = *(const float4*)(Et + e * 68 + rq * 4);
        float4 sv = *(const float4*)(Sl + e * 64 + cq * 4);
        a00 = fmaf(ev.x, sv.x, a00); a01 = fmaf(ev.x, sv.y, a01);
        a02 = fmaf(ev.x, sv.z, a02); a03 = fmaf(ev.x, sv.w, a03);
        a10 = fmaf(ev.y, sv.x, a10); a11 = fmaf(ev.y, sv.y, a11);
        a12 = fmaf(ev.y, sv.z, a12); a13 = fmaf(ev.y, sv.w, a13);
        a20 = fmaf(ev.z, sv.x, a20); a21 = fmaf(ev.z, sv.y, a21);
        a22 = fmaf(ev.z, sv.z, a22); a23 = fmaf(ev.z, sv.w, a23);
        a30 = fmaf(ev.w, sv.x, a30); a31 = fmaf(ev.w, sv.y, a31);
        a32 = fmaf(ev.w, sv.z, a32); a33 = fmaf(ev.w, sv.w, a33);
    }

    const int r0 = vbase + rq * 4;
    float4 o0 = make_float4(a00, a01, a02, a03);
    float4 o1 = make_float4(a10, a11, a12, a13);
    float4 o2 = make_float4(a20, a21, a22, a23);
    float4 o3 = make_float4(a30, a31, a32, a33);
    if (r0 == 0) o0 = make_float4(0.f, 0.f, 0.f, 0.f);  // padding_idx=0
    if (r0 + 0 < NVOC) *(float4*)(P + (r0 + 0) * 64 + cq * 4) = o0;
    if (r0 + 1 < NVOC) *(float4*)(P + (r0 + 1) * 64 + cq * 4) = o1;
    if (r0 + 2 < NVOC) *(float4*)(P + (r0 + 2) * 64 + cq * 4) = o2;
    if (r0 + 3 < NVOC) *(float4*)(P + (r0 + 3) * 64 + cq * 4) = o3;
}

// ---------------------------------------------------------------------------
// Kernel 2: one batch row per block (256 threads = 4 waves).
// Arithmetic VERBATIM from passing rounds 5/6/10 (absmax 4.88e-4; 128.4 us,
// VGPR 56, occ 41%).
// ONE change vs r10: amdgpu_waves_per_eu(4,8) -> (7,8).
// Session facts: occupancy tracks the DECLARED min waves/EU and never floats
// above it (r10); launch_bounds 2nd arg >=5 force-spills pathologically
// (r1/r7/r8/r12) but waves_per_eu behaves sanely (r9: min=6 need-40 no-spill;
// r10: min=4 need-56 no-spill). min=7 budget = 512/7 ~ 73 VGPR >= 56 needed
// (17-reg margin) -> expect no spill + occupancy ~72%.
// Canaries: VGPR < 50 or WRITE >> 4 MB = spill -> revert to r6 config.
// If occ rises to ~70% but dur stays ~128 us: barrier/serial-chain floor,
// structure is at its limit.
//
// LDS pool 17344 B:
//   Bm    [0    .. 832)   [k*208 + l]
//   W4    [832  .. 1632)  [l*4 + k]
//   caps4 [1632 .. 1888)  [d*4 + k]
//   bigneg[1888 .. 2088)
//   idxs  [2088 .. 2288)  int[200], live whole kernel
//   SC    [2288 .. 4336)  union: part[1024] | h4 = SC+1024
// ---------------------------------------------------------------------------
__global__ __launch_bounds__(256)
__attribute__((amdgpu_waves_per_eu(7, 8)))
void mind_row(
    const int*   __restrict__ his, const float* __restrict__ P,
    const float* __restrict__ B0,  const float* __restrict__ W1,
    const float* __restrict__ b1,  const float* __restrict__ W2,
    const float* __restrict__ b2,  float* __restrict__ out)
{
    __shared__ __align__(16) float POOL[4336];
    float* Bm     = POOL;          // [k*208 + l]
    float* W4     = POOL + 832;    // [l*4 + k]
    float* caps4  = POOL + 1632;   // [d*4 + k]
    float* bigneg = POOL + 1888;   // [200]
    int*   idxs   = (int*)(POOL + 2088);   // [200], live whole kernel
    float* SC     = POOL + 2288;   // 2048-float union
    float* part   = SC;            // [q*256 + k*64 + d]  (phase B -> C; MLP2)
    float* h4     = SC + 1024;     // [f*4 + k]           (MLP)

    const int b    = blockIdx.x;
    const int tid  = threadIdx.x;
    const int lane = tid & 63;
    const int wv   = tid >> 6;

    // ---- setup -------------------------------------------------------------
    for (int l = tid; l < LSEQ; l += 256) {
        int id = his[b * LSEQ + l];
        idxs[l]   = id;
        bigneg[l] = (id != 0) ? 0.f : -1e30f;
    }
    if (tid < LSEQ) {
        #pragma unroll
        for (int k = 0; k < KCAP; k++) Bm[k * 208 + tid] = B0[k * LSEQ + tid];
    }
    __syncthreads();

    // ---- gather hisP rows: wave covers l in [wv*50, wv*50+50), lane = d ----
    float hp[50];
    #pragma unroll
    for (int i = 0; i < 50; i++) {
        int l = wv * 50 + i;
        hp[i] = P[idxs[l] * 64 + lane];     // 256B coalesced per wave; row0=0
    }

    for (int r = 0; r < 3; r++) {
        // A: masked softmax over l, capsule k = wv (one wave per capsule)
        {
            const float* Bk = Bm + wv * 208;
            float x0 = Bk[lane]       + bigneg[lane];
            float x1 = Bk[lane + 64]  + bigneg[lane + 64];
            float x2 = Bk[lane + 128] + bigneg[lane + 128];
            float x3 = (lane < 8) ? (Bk[lane + 192] + bigneg[lane + 192]) : -3.0e38f;
            float m = fmaxf(fmaxf(x0, x1), fmaxf(x2, x3));
            #pragma unroll
            for (int off = 32; off; off >>= 1) m = fmaxf(m, __shfl_xor(m, off, 64));
            float e0 = __expf(x0 - m), e1 = __expf(x1 - m), e2 = __expf(x2 - m);
            float e3 = (lane < 8) ? __expf(x3 - m) : 0.f;
            float ssum = e0 + e1 + e2 + e3;
            #pragma unroll
            for (int off = 32; off; off >>= 1) ssum += __shfl_xor(ssum, off, 64);
            float inv = 1.f / ssum;
            W4[lane * 4 + wv]         = e0 * inv;
            W4[(lane + 64) * 4 + wv]  = e1 * inv;
            W4[(lane + 128) * 4 + wv] = e2 * inv;
            if (lane < 8) W4[(lane + 192) * 4 + wv] = e3 * inv;
        }
        __syncthreads();

        // B: caps partials from register-resident hisP (exact ref summands)
        {
            float a0 = 0, a1 = 0, a2 = 0, a3 = 0;
            #pragma unroll
            for (int i = 0; i < 50; i++) {
                int l = wv * 50 + i;
                float4 w = *(const float4*)(W4 + l * 4);   // broadcast b128
                float  v = hp[i];
                a0 = fmaf(w.x, v, a0);
                a1 = fmaf(w.y, v, a1);
                a2 = fmaf(w.z, v, a2);
                a3 = fmaf(w.w, v, a3);
            }
            part[wv * 256 + lane]       = a0;
            part[wv * 256 + 64 + lane]  = a1;
            part[wv * 256 + 128 + lane] = a2;
            part[wv * 256 + 192 + lane] = a3;
        }
        __syncthreads();

        // C: reduce partials + squash; thread = (k = wv, d = lane)
        {
            float c = part[wv * 64 + lane]       + part[256 + wv * 64 + lane]
                    + part[512 + wv * 64 + lane] + part[768 + wv * 64 + lane];
            float n2 = c * c;
            #pragma unroll
            for (int off = 32; off; off >>= 1) n2 += __shfl_xor(n2, off, 64);
            float n  = sqrtf(n2);
            float sc = n2 / ((1.f + n2) * n + 1e-9f);
            c *= sc;
            caps4[lane * 4 + wv] = c;
        }
        __syncthreads();

        if (r < 2) {
            // D: B[k][l] += caps[k] . hisP[l]  (thread per l). hisP row
            // re-read from global P (L1/L2-hot). d ascending -> bit-identical.
            if (tid < LSEQ) {
                const float4* __restrict__ rowp = (const float4*)(P + idxs[tid] * 64);
                float d0 = 0, d1 = 0, d2 = 0, d3 = 0;
                #pragma unroll
                for (int j = 0; j < 16; j++) {
                    float4 v = rowp[j];
                    {
                        float4 c = *(const float4*)(caps4 + (j * 4 + 0) * 4);
                        d0 = fmaf(c.x, v.x, d0); d1 = fmaf(c.y, v.x, d1);
                        d2 = fmaf(c.z, v.x, d2); d3 = fmaf(c.w, v.x, d3);
                    }
                    {
                        float4 c = *(const float4*)(caps4 + (j * 4 + 1) * 4);
                        d0 = fmaf(c.x, v.y, d0); d1 = fmaf(c.y, v.y, d1);
                        d2 = fmaf(c.z, v.y, d2); d3 = fmaf(c.w, v.y, d3);
                    }
                    {
                        float4 c = *(const float4*)(caps4 + (j * 4 + 2) * 4);
                        d0 = fmaf(c.x, v.z, d0); d1 = fmaf(c.y, v.z, d1);
                        d2 = fmaf(c.z, v.z, d2); d3 = fmaf(c.w, v.z, d3);
                    }
                    {
                        float4 c = *(const float4*)(caps4 + (j * 4 + 3) * 4);
                        d0 = fmaf(c.x, v.w, d0); d1 = fmaf(c.y, v.w, d1);
                        d2 = fmaf(c.z, v.w, d2); d3 = fmaf(c.w, v.w, d3);
                    }
                }
                Bm[tid]       += d0;
                Bm[208 + tid] += d1;
                Bm[416 + tid] += d2;
                Bm[624 + tid] += d3;
            }
            __syncthreads();
        }
    }

    // MLP layer 1: h = relu(caps @ W1 + b1), h4[f*4+k]
    {
        const int f = tid;
        float h0 = 0, h1 = 0, h2 = 0, h3 = 0;
        #pragma unroll 8
        for (int d = 0; d < 64; d++) {
            float  w = W1[d * 256 + f];                      // coalesced, L2-hot
            float4 c = *(const float4*)(caps4 + d * 4);
            h0 = fmaf(c.x, w, h0);
            h1 = fmaf(c.y, w, h1);
            h2 = fmaf(c.z, w, h2);
            h3 = fmaf(c.w, w, h3);
        }
        float bb = b1[f];
        h0 = fmaxf(h0 + bb, 0.f);
        h1 = fmaxf(h1 + bb, 0.f);
        h2 = fmaxf(h2 + bb, 0.f);
        h3 = fmaxf(h3 + bb, 0.f);
        h4[f * 4 + 0] = h0; h4[f * 4 + 1] = h1;
        h4[f * 4 + 2] = h2; h4[f * 4 + 3] = h3;
    }
    __syncthreads();

    // MLP layer 2 partials: q = wv covers f in [q*64, q*64+64), d = lane
    {
        float o0 = 0, o1 = 0, o2 = 0, o3 = 0;
        #pragma unroll 8
        for (int i = 0; i < 64; i++) {
            int f = wv * 64 + i;
            float  w  = W2[f * 64 + lane];                   // coalesced, L2-hot
            float4 hv = *(const float4*)(h4 + f * 4);        // broadcast b128
            o0 = fmaf(hv.x, w, o0);
            o1 = fmaf(hv.y, w, o1);
            o2 = fmaf(hv.z, w, o2);
            o3 = fmaf(hv.w, w, o3);
        }
        part[wv * 256 + lane]       = o0;
        part[wv * 256 + 64 + lane]  = o1;
        part[wv * 256 + 128 + lane] = o2;
        part[wv * 256 + 192 + lane] = o3;
    }
    __syncthreads();
    {
        float o = part[wv * 64 + lane]       + part[256 + wv * 64 + lane]
                + part[512 + wv * 64 + lane] + part[768 + wv * 64 + lane];
        out[b * 256 + tid] = o + b2[lane];   // (b, k=wv, d=lane) contiguous
    }
}

extern "C" void kernel_launch(void* const* d_in, const int* in_sizes, int n_in,
                              void* d_out, int out_size, void* d_ws, size_t ws_size,
                              hipStream_t stream) {
    const int*   his = (const int*)  d_in[0];
    const float* E   = (const float*)d_in[1];
    const float* S   = (const float*)d_in[2];
    const float* B0  = (const float*)d_in[3];
    const float* W1  = (const float*)d_in[4];
    const float* b1  = (const float*)d_in[5];
    const float* W2  = (const float*)d_in[6];
    const float* b2  = (const float*)d_in[7];
    float* out = (float*)d_out;
    float* P   = (float*)d_ws;            // NVOC*64 floats = 25.6 MB scratch

    precompute_P<<<(NVOC + 63) / 64, 256, 0, stream>>>(E, S, P);
    mind_row<<<4096, 256, 0, stream>>>(his, P, B0, W1, b1, W2, b2, out);
}

// Round 15
// 232.567 us; speedup vs baseline: 1.4433x; 1.1903x over previous
//
#include <hip/hip_runtime.h>

#define LSEQ 200
#define KCAP 4
#define NVOC 100000

// ---------------------------------------------------------------------------
// Kernel 1: P = (E with row 0 zeroed) @ S, P: (NVOC, 64) in workspace.
// Verbatim round-6 version (passed; ~13 us). 64x64 tile, 4x4 per-thread.
// ---------------------------------------------------------------------------
__global__ __launch_bounds__(256) void precompute_P(
    const float* __restrict__ E, const float* __restrict__ S,
    float* __restrict__ P)
{
    __shared__ __align__(16) float Sl[64 * 64];   // Sl[e*64 + d]
    __shared__ __align__(16) float Et[64 * 68];   // Et[e*68 + r] = E[(vbase+r)*64+e]
    const int tid   = threadIdx.x;
    const int vbase = blockIdx.x * 64;

    #pragma unroll
    for (int t = tid; t < 4096; t += 256) Sl[t] = S[t];
    #pragma unroll
    for (int t = tid; t < 4096; t += 256) {
        int r = t >> 6, e = t & 63;               // wave: r fixed, e=lane -> coalesced
        int v = vbase + r;
        Et[e * 68 + r] = (v < NVOC) ? E[v * 64 + e] : 0.f;
    }
    __syncthreads();

    const int rq = tid >> 4;                      // 16 row-quads
    const int cq = tid & 15;                      // 16 col-quads
    float a00=0,a01=0,a02=0,a03=0, a10=0,a11=0,a12=0,a13=0;
    float a20=0,a21=0,a22=0,a23=0, a30=0,a31=0,a32=0,a33=0;
    #pragma unroll 8
    for (int e = 0; e < 64; e++) {
        float4 ev = *(const float4*)(Et + e * 68 + rq * 4);
        float4 sv = *(const float4*)(Sl + e * 64 + cq * 4);
        a00 = fmaf(ev.x, sv.x, a00); a01 = fmaf(ev.x, sv.y, a01);
        a02 = fmaf(ev.x, sv.z, a02); a03 = fmaf(ev.x, sv.w, a03);
        a10 = fmaf(ev.y, sv.x, a10); a11 = fmaf(ev.y, sv.y, a11);
        a12 = fmaf(ev.y, sv.z, a12); a13 = fmaf(ev.y, sv.w, a13);
        a20 = fmaf(ev.z, sv.x, a20); a21 = fmaf(ev.z, sv.y, a21);
        a22 = fmaf(ev.z, sv.z, a22); a23 = fmaf(ev.z, sv.w, a23);
        a30 = fmaf(ev.w, sv.x, a30); a31 = fmaf(ev.w, sv.y, a31);
        a32 = fmaf(ev.w, sv.z, a32); a33 = fmaf(ev.w, sv.w, a33);
    }

    const int r0 = vbase + rq * 4;
    float4 o0 = make_float4(a00, a01, a02, a03);
    float4 o1 = make_float4(a10, a11, a12, a13);
    float4 o2 = make_float4(a20, a21, a22, a23);
    float4 o3 = make_float4(a30, a31, a32, a33);
    if (r0 == 0) o0 = make_float4(0.f, 0.f, 0.f, 0.f);  // padding_idx=0
    if (r0 + 0 < NVOC) *(float4*)(P + (r0 + 0) * 64 + cq * 4) = o0;
    if (r0 + 1 < NVOC) *(float4*)(P + (r0 + 1) * 64 + cq * 4) = o1;
    if (r0 + 2 < NVOC) *(float4*)(P + (r0 + 2) * 64 + cq * 4) = o2;
    if (r0 + 3 < NVOC) *(float4*)(P + (r0 + 3) * 64 + cq * 4) = o3;
}

// ---------------------------------------------------------------------------
// Kernel 2: one batch row per block (256 threads = 4 waves).
// Arithmetic VERBATIM from passing rounds 5/6/10 (absmax 4.88e-4; 128.4 us,
// VGPR 56, occ 41%).
// ONE change vs r10: amdgpu_waves_per_eu(4,8) -> (5,8). FINAL occupancy
// experiment, pre-committed decision rule:
//   - Allocator model (r9/r10/r14): spill iff pre-RA pressure estimate
//     (~75 here) exceeds the min-waves budget (512/min). min=5 -> 102 > 75
//     -> predict HOLD at VGPR 56, occ ~52%, dur ~112-122 us.
//   - If spill canary fires (VGPR < 50, WRITE >> 4 MB): wpe == lb at min>=5
//     for this pressure; 41%-occ/128 us is the structure's practical floor
//     (all escapes measured+closed: LDS-hisP 148, global re-read 226,
//     512-thr 142, dual-row 240, lb>=5 & wpe>=7 spill) -> revert to r10 and
//     conclude.
//
// LDS pool 17344 B (allows 5+ blocks/CU):
//   Bm    [0    .. 832)   [k*208 + l]
//   W4    [832  .. 1632)  [l*4 + k]
//   caps4 [1632 .. 1888)  [d*4 + k]
//   bigneg[1888 .. 2088)
//   idxs  [2088 .. 2288)  int[200], live whole kernel
//   SC    [2288 .. 4336)  union: part[1024] | h4 = SC+1024
// ---------------------------------------------------------------------------
__global__ __launch_bounds__(256)
__attribute__((amdgpu_waves_per_eu(5, 8)))
void mind_row(
    const int*   __restrict__ his, const float* __restrict__ P,
    const float* __restrict__ B0,  const float* __restrict__ W1,
    const float* __restrict__ b1,  const float* __restrict__ W2,
    const float* __restrict__ b2,  float* __restrict__ out)
{
    __shared__ __align__(16) float POOL[4336];
    float* Bm     = POOL;          // [k*208 + l]
    float* W4     = POOL + 832;    // [l*4 + k]
    float* caps4  = POOL + 1632;   // [d*4 + k]
    float* bigneg = POOL + 1888;   // [200]
    int*   idxs   = (int*)(POOL + 2088);   // [200], live whole kernel
    float* SC     = POOL + 2288;   // 2048-float union
    float* part   = SC;            // [q*256 + k*64 + d]  (phase B -> C; MLP2)
    float* h4     = SC + 1024;     // [f*4 + k]           (MLP)

    const int b    = blockIdx.x;
    const int tid  = threadIdx.x;
    const int lane = tid & 63;
    const int wv   = tid >> 6;

    // ---- setup -------------------------------------------------------------
    for (int l = tid; l < LSEQ; l += 256) {
        int id = his[b * LSEQ + l];
        idxs[l]   = id;
        bigneg[l] = (id != 0) ? 0.f : -1e30f;
    }
    if (tid < LSEQ) {
        #pragma unroll
        for (int k = 0; k < KCAP; k++) Bm[k * 208 + tid] = B0[k * LSEQ + tid];
    }
    __syncthreads();

    // ---- gather hisP rows: wave covers l in [wv*50, wv*50+50), lane = d ----
    float hp[50];
    #pragma unroll
    for (int i = 0; i < 50; i++) {
        int l = wv * 50 + i;
        hp[i] = P[idxs[l] * 64 + lane];     // 256B coalesced per wave; row0=0
    }

    for (int r = 0; r < 3; r++) {
        // A: masked softmax over l, capsule k = wv (one wave per capsule)
        {
            const float* Bk = Bm + wv * 208;
            float x0 = Bk[lane]       + bigneg[lane];
            float x1 = Bk[lane + 64]  + bigneg[lane + 64];
            float x2 = Bk[lane + 128] + bigneg[lane + 128];
            float x3 = (lane < 8) ? (Bk[lane + 192] + bigneg[lane + 192]) : -3.0e38f;
            float m = fmaxf(fmaxf(x0, x1), fmaxf(x2, x3));
            #pragma unroll
            for (int off = 32; off; off >>= 1) m = fmaxf(m, __shfl_xor(m, off, 64));
            float e0 = __expf(x0 - m), e1 = __expf(x1 - m), e2 = __expf(x2 - m);
            float e3 = (lane < 8) ? __expf(x3 - m) : 0.f;
            float ssum = e0 + e1 + e2 + e3;
            #pragma unroll
            for (int off = 32; off; off >>= 1) ssum += __shfl_xor(ssum, off, 64);
            float inv = 1.f / ssum;
            W4[lane * 4 + wv]         = e0 * inv;
            W4[(lane + 64) * 4 + wv]  = e1 * inv;
            W4[(lane + 128) * 4 + wv] = e2 * inv;
            if (lane < 8) W4[(lane + 192) * 4 + wv] = e3 * inv;
        }
        __syncthreads();

        // B: caps partials from register-resident hisP (exact ref summands)
        {
            float a0 = 0, a1 = 0, a2 = 0, a3 = 0;
            #pragma unroll
            for (int i = 0; i < 50; i++) {
                int l = wv * 50 + i;
                float4 w = *(const float4*)(W4 + l * 4);   // broadcast b128
                float  v = hp[i];
                a0 = fmaf(w.x, v, a0);
                a1 = fmaf(w.y, v, a1);
                a2 = fmaf(w.z, v, a2);
                a3 = fmaf(w.w, v, a3);
            }
            part[wv * 256 + lane]       = a0;
            part[wv * 256 + 64 + lane]  = a1;
            part[wv * 256 + 128 + lane] = a2;
            part[wv * 256 + 192 + lane] = a3;
        }
        __syncthreads();

        // C: reduce partials + squash; thread = (k = wv, d = lane)
        {
            float c = part[wv * 64 + lane]       + part[256 + wv * 64 + lane]
                    + part[512 + wv * 64 + lane] + part[768 + wv * 64 + lane];
            float n2 = c * c;
            #pragma unroll
            for (int off = 32; off; off >>= 1) n2 += __shfl_xor(n2, off, 64);
            float n  = sqrtf(n2);
            float sc = n2 / ((1.f + n2) * n + 1e-9f);
            c *= sc;
            caps4[lane * 4 + wv] = c;
        }
        __syncthreads();

        if (r < 2) {
            // D: B[k][l] += caps[k] . hisP[l]  (thread per l). hisP row
            // re-read from global P (L1/L2-hot). d ascending -> bit-identical.
            if (tid < LSEQ) {
                const float4* __restrict__ rowp = (const float4*)(P + idxs[tid] * 64);
                float d0 = 0, d1 = 0, d2 = 0, d3 = 0;
                #pragma unroll
                for (int j = 0; j < 16; j++) {
                    float4 v = rowp[j];
                    {
                        float4 c = *(const float4*)(caps4 + (j * 4 + 0) * 4);
                        d0 = fmaf(c.x, v.x, d0); d1 = fmaf(c.y, v.x, d1);
                        d2 = fmaf(c.z, v.x, d2); d3 = fmaf(c.w, v.x, d3);
                    }
                    {
                        float4 c = *(const float4*)(caps4 + (j * 4 + 1) * 4);
                        d0 = fmaf(c.x, v.y, d0); d1 = fmaf(c.y, v.y, d1);
                        d2 = fmaf(c.z, v.y, d2); d3 = fmaf(c.w, v.y, d3);
                    }
                    {
                        float4 c = *(const float4*)(caps4 + (j * 4 + 2) * 4);
                        d0 = fmaf(c.x, v.z, d0); d1 = fmaf(c.y, v.z, d1);
                        d2 = fmaf(c.z, v.z, d2); d3 = fmaf(c.w, v.z, d3);
                    }
                    {
                        float4 c = *(const float4*)(caps4 + (j * 4 + 3) * 4);
                        d0 = fmaf(c.x, v.w, d0); d1 = fmaf(c.y, v.w, d1);
                        d2 = fmaf(c.z, v.w, d2); d3 = fmaf(c.w, v.w, d3);
                    }
                }
                Bm[tid]       += d0;
                Bm[208 + tid] += d1;
                Bm[416 + tid] += d2;
                Bm[624 + tid] += d3;
            }
            __syncthreads();
        }
    }

    // MLP layer 1: h = relu(caps @ W1 + b1), h4[f*4+k]
    {
        const int f = tid;
        float h0 = 0, h1 = 0, h2 = 0, h3 = 0;
        #pragma unroll 8
        for (int d = 0; d < 64; d++) {
            float  w = W1[d * 256 + f];                      // coalesced, L2-hot
            float4 c = *(const float4*)(caps4 + d * 4);
            h0 = fmaf(c.x, w, h0);
            h1 = fmaf(c.y, w, h1);
            h2 = fmaf(c.z, w, h2);
            h3 = fmaf(c.w, w, h3);
        }
        float bb = b1[f];
        h0 = fmaxf(h0 + bb, 0.f);
        h1 = fmaxf(h1 + bb, 0.f);
        h2 = fmaxf(h2 + bb, 0.f);
        h3 = fmaxf(h3 + bb, 0.f);
        h4[f * 4 + 0] = h0; h4[f * 4 + 1] = h1;
        h4[f * 4 + 2] = h2; h4[f * 4 + 3] = h3;
    }
    __syncthreads();

    // MLP layer 2 partials: q = wv covers f in [q*64, q*64+64), d = lane
    {
        float o0 = 0, o1 = 0, o2 = 0, o3 = 0;
        #pragma unroll 8
        for (int i = 0; i < 64; i++) {
            int f = wv * 64 + i;
            float  w  = W2[f * 64 + lane];                   // coalesced, L2-hot
            float4 hv = *(const float4*)(h4 + f * 4);        // broadcast b128
            o0 = fmaf(hv.x, w, o0);
            o1 = fmaf(hv.y, w, o1);
            o2 = fmaf(hv.z, w, o2);
            o3 = fmaf(hv.w, w, o3);
        }
        part[wv * 256 + lane]       = o0;
        part[wv * 256 + 64 + lane]  = o1;
        part[wv * 256 + 128 + lane] = o2;
        part[wv * 256 + 192 + lane] = o3;
    }
    __syncthreads();
    {
        float o = part[wv * 64 + lane]       + part[256 + wv * 64 + lane]
                + part[512 + wv * 64 + lane] + part[768 + wv * 64 + lane];
        out[b * 256 + tid] = o + b2[lane];   // (b, k=wv, d=lane) contiguous
    }
}

extern "C" void kernel_launch(void* const* d_in, const int* in_sizes, int n_in,
                              void* d_out, int out_size, void* d_ws, size_t ws_size,
                              hipStream_t stream) {
    const int*   his = (const int*)  d_in[0];
    const float* E   = (const float*)d_in[1];
    const float* S   = (const float*)d_in[2];
    const float* B0  = (const float*)d_in[3];
    const float* W1  = (const float*)d_in[4];
    const float* b1  = (const float*)d_in[5];
    const float* W2  = (const float*)d_in[6];
    const float* b2  = (const float*)d_in[7];
    float* out = (float*)d_out;
    float* P   = (float*)d_ws;            // NVOC*64 floats = 25.6 MB scratch

    precompute_P<<<(NVOC + 63) / 64, 256, 0, stream>>>(E, S, P);
    mind_row<<<4096, 256, 0, stream>>>(his, P, B0, W1, b1, W2, b2, out);
}